// Round 5
// baseline (458.638 us; speedup 1.0000x reference)
//
#include <hip/hip_runtime.h>

// SpMM: out[b,m] = bias[m] + sum_{e: dst[e]==m} values[e] * x[b, src[e]]
// B=32, N=M=50000, E=1600000.
//
// R5: CSR-by-bucket build (count/scan/fill) + accum with full-line gathers,
// SEG=2 record split per bucket, depth-4 chunked pipeline, LDS accumulate,
// coalesced atomic merge into out_t, final fused transpose+bias.
// R1: global fp32 atomics write through (204.8 MB) — avoid per-edge atomics.
// R2: random 8B scatter costs a 64B line each; single-block 50k scan serializes.
// R3: 391-block accum latency-starved (occ 25%, VALU 3%).
// R4: batch-splitting the gather quadruples traffic (195 MB) — keep 32-lane
//     full-line gathers; get MLP from chunking instead.

#define BATCH  32
#define ROWB   128            // dst rows per bucket
#define KP     512            // padded max bucket count (M <= 65536)
#define EPB    4096           // edges per fill block
#define FILL_T 512
#define ACC_T  512
#define SEG    2              // record segments per bucket

// ---- x (B,N) -> xt (N,B), LDS tiled ----
__global__ void k_transpose_x(const float* __restrict__ x, float* __restrict__ xt, int N) {
    __shared__ float tile[32][33];
    const int n0 = blockIdx.x * 32;
    const int tx = threadIdx.x;
    const int ty = threadIdx.y;
    #pragma unroll
    for (int k = 0; k < 4; ++k) {
        const int b = ty + 8 * k;
        const int n = n0 + tx;
        tile[tx][b] = (n < N) ? x[(size_t)b * N + n] : 0.0f;
    }
    __syncthreads();
    #pragma unroll
    for (int k = 0; k < 4; ++k) {
        const int n = n0 + ty + 8 * k;
        if (n < N) xt[(size_t)n * BATCH + tx] = tile[ty + 8 * k][tx];
    }
}

// ---- bucket counts (LDS-privatized histogram over K buckets) ----
__global__ void k_count(const int* __restrict__ idx, int* __restrict__ cnt, int E, int K) {
    __shared__ int h[KP];
    for (int i = threadIdx.x; i < K; i += blockDim.x) h[i] = 0;
    __syncthreads();
    const int stride = gridDim.x * blockDim.x;
    for (int e = blockIdx.x * blockDim.x + threadIdx.x; e < E; e += stride)
        atomicAdd(&h[idx[E + e] >> 7], 1);
    __syncthreads();
    for (int i = threadIdx.x; i < K; i += blockDim.x)
        if (h[i]) atomicAdd(&cnt[i], h[i]);
}

// ---- exclusive scan over K (<=512) bucket counts; one block of 512 ----
__global__ void k_scan(const int* __restrict__ cnt, int* __restrict__ start,
                       int* __restrict__ cursor, int K, int E) {
    __shared__ int sa[KP], sb[KP];
    const int t = threadIdx.x;               // 512 threads
    const int v = (t < K) ? cnt[t] : 0;
    sa[t] = v;
    __syncthreads();
    int* a = sa; int* b = sb;
    for (int off = 1; off < KP; off <<= 1) {
        b[t] = a[t] + ((t >= off) ? a[t - off] : 0);
        __syncthreads();
        int* tmp = a; a = b; b = tmp;
    }
    const int excl = a[t] - v;               // a = inclusive scan
    if (t < K) { start[t] = excl; cursor[t] = excl; }
    if (t == K - 1) start[K] = a[t];         // == E
}

// ---- fill: LDS-staged grouping by bucket, grouped coalesced flush ----
__global__ void k_fill(const int* __restrict__ idx, const float* __restrict__ values,
                       int* __restrict__ cursor, int2* __restrict__ records, int E, int K) {
    __shared__ int2 stage[EPB];              // 32 KB
    __shared__ int sa[KP], sb[KP];           // scan double-buffer
    __shared__ int lscan[KP + 1];
    __shared__ int lgbase[KP];

    const int t = threadIdx.x;               // 512
    const int base = blockIdx.x * EPB;
    const int total = min(EPB, E - base);

    sa[t] = 0;
    __syncthreads();
    // phase 1: local histogram
    for (int i = t; i < total; i += FILL_T)
        atomicAdd(&sa[idx[E + base + i] >> 7], 1);
    __syncthreads();
    const int myc = sa[t];                   // this thread's bucket count
    __syncthreads();
    // Hillis-Steele inclusive scan over KP entries
    int* a = sa; int* b = sb;
    for (int off = 1; off < KP; off <<= 1) {
        b[t] = a[t] + ((t >= off) ? a[t - off] : 0);
        __syncthreads();
        int* tmp = a; a = b; b = tmp;
    }
    lscan[t] = a[t] - myc;                   // exclusive; == total for t >= K
    if (t == 0) lscan[KP] = total;
    // reserve global range for this (block,bucket); reuse dead scan buffer as lcur
    int* lcur = b;
    lcur[t] = 0;
    lgbase[t] = (t < K && myc > 0) ? atomicAdd(&cursor[t], myc) : 0;
    __syncthreads();
    // phase 2: re-read edges, place grouped-by-bucket into LDS staging
    for (int i = t; i < total; i += FILL_T) {
        const int e = base + i;
        const int src = idx[e];
        const int dst = idx[E + e];
        const float v = values[e];
        const int bk = dst >> 7;
        const int pos = lscan[bk] + atomicAdd(&lcur[bk], 1);
        stage[pos] = make_int2(src | ((dst & 127) << 16), __float_as_int(v));
    }
    __syncthreads();
    // phase 3: flush — consecutive staging slots within a bucket map to
    // consecutive global addresses
    for (int i = t; i < total; i += FILL_T) {
        int bpos = 0;
        #pragma unroll
        for (int s = 256; s > 0; s >>= 1) {
            const int nb = bpos + s;
            if (nb < KP && lscan[nb] <= i) bpos = nb;
        }
        records[lgbase[bpos] + (i - lscan[bpos])] = stage[i];
    }
}

// ---- accum: grid (SEG, K); 512 thr = 16 streams x 32 lanes; full-line
//      gathers; depth-4 chunk pipeline; LDS accumulate; atomic merge ----
__global__ void k_accum(const float* __restrict__ xt, const int2* __restrict__ records,
                        const int* __restrict__ start, float* __restrict__ out_t, int M) {
    __shared__ float acc[ROWB * 33];         // 16.9 KB, conflict-free
    const int t   = threadIdx.x;             // 512
    const int seg = blockIdx.x;              // 0..SEG-1
    const int bk  = blockIdx.y;
    const int b   = t & 31;
    const int s   = t >> 5;                  // 0..15 stream id

    for (int i = t; i < ROWB * 33; i += ACC_T) acc[i] = 0.0f;
    __syncthreads();

    const int jb = start[bk], je = start[bk + 1];
    const int len  = je - jb;
    const int half = (len + SEG - 1) / SEG;
    const int lo   = jb + seg * half;
    const int hi   = min(lo + half, je);

    int i = lo + s * 4;
    int2 pr[4];
    #pragma unroll
    for (int c = 0; c < 4; ++c)
        pr[c] = (i + c < hi) ? records[i + c] : make_int2(0, 0);

    while (i < hi) {
        float xv[4];
        #pragma unroll
        for (int c = 0; c < 4; ++c)
            xv[c] = xt[((size_t)(pr[c].x & 0xFFFF) << 5) + b];
        const int ni = i + 64;               // 16 streams x 4 records
        int2 nr[4];
        #pragma unroll
        for (int c = 0; c < 4; ++c)
            nr[c] = (ni + c < hi) ? records[ni + c] : make_int2(0, 0);
        #pragma unroll
        for (int c = 0; c < 4; ++c)
            atomicAdd(&acc[((pr[c].x >> 16) & 127) * 33 + b],
                      __int_as_float(pr[c].y) * xv[c]);
        #pragma unroll
        for (int c = 0; c < 4; ++c) pr[c] = nr[c];
        i = ni;
    }
    __syncthreads();

    // coalesced atomic merge: out_t is (K*ROWB, 32) row-major
    const size_t base = (size_t)bk * (ROWB * BATCH);
    for (int k = t; k < ROWB * BATCH; k += ACC_T)
        atomicAdd(&out_t[base + k], acc[(k >> 5) * 33 + (k & 31)]);
}

// ---- out_t (M,32) -> out (32,M) + bias, LDS tiled ----
__global__ void k_transpose_out(const float* __restrict__ out_t, const float* __restrict__ bias,
                                float* __restrict__ out, int M) {
    __shared__ float tile[32][33];
    const int m0 = blockIdx.x * 32;
    const int tx = threadIdx.x;
    const int ty = threadIdx.y;
    #pragma unroll
    for (int k = 0; k < 4; ++k) {
        const int m = m0 + ty + 8 * k;
        if (m < M) tile[ty + 8 * k][tx] = out_t[(size_t)m * BATCH + tx];
    }
    __syncthreads();
    #pragma unroll
    for (int k = 0; k < 4; ++k) {
        const int b = ty + 8 * k;
        const int m = m0 + tx;
        if (m < M) out[(size_t)b * M + m] = tile[tx][b] + bias[m];
    }
}

extern "C" void kernel_launch(void* const* d_in, const int* in_sizes, int n_in,
                              void* d_out, int out_size, void* d_ws, size_t ws_size,
                              hipStream_t stream) {
    const float* x      = (const float*)d_in[0];  // (B,N,1) fp32
    const float* values = (const float*)d_in[1];  // (E,)    fp32
    const float* bias   = (const float*)d_in[2];  // (M,1)   fp32
    const int*   idx    = (const int*)d_in[3];    // (2,E)   int32

    const int N = in_sizes[0] / BATCH;   // 50000
    const int E = in_sizes[3] / 2;       // 1600000
    const int M = in_sizes[2];           // 50000
    const int K = (M + ROWB - 1) / ROWB; // 391

    float* out = (float*)d_out;

    // workspace: records (E int2, 12.8 MB) | xt (6.4 MB) | out_t (K*128*32 f32,
    // 6.41 MB — padded past M) | cnt | start | cursor   => ~25.7 MB
    char* p = (char*)d_ws;
    int2*  records = (int2*)p;           p += (size_t)E * sizeof(int2);
    float* xt      = (float*)p;          p += (size_t)N * BATCH * sizeof(float);
    float* out_t   = (float*)p;          p += (size_t)K * ROWB * BATCH * sizeof(float);
    int*   cnt     = (int*)p;            p += (size_t)K * sizeof(int);
    int*   start   = (int*)p;            p += (size_t)(K + 1) * sizeof(int);
    int*   cursor  = (int*)p;

    hipMemsetAsync(cnt, 0, (size_t)K * sizeof(int), stream);
    hipMemsetAsync(out_t, 0, (size_t)K * ROWB * BATCH * sizeof(float), stream);

    dim3 tblk(32, 8);
    k_transpose_x<<<(N + 31) / 32, tblk, 0, stream>>>(x, xt, N);
    k_count<<<256, 256, 0, stream>>>(idx, cnt, E, K);
    k_scan<<<1, KP, 0, stream>>>(cnt, start, cursor, K, E);
    k_fill<<<(E + EPB - 1) / EPB, FILL_T, 0, stream>>>(idx, values, cursor, records, E, K);

    dim3 agrid(SEG, K);
    k_accum<<<agrid, ACC_T, 0, stream>>>(xt, records, start, out_t, M);
    k_transpose_out<<<(M + 31) / 32, tblk, 0, stream>>>(out_t, bias, out, M);
}

// Round 6
// 294.912 us; speedup vs baseline: 1.5552x; 1.5552x over previous
//
#include <hip/hip_runtime.h>

// SpMM: out[b,m] = bias[m] + sum_{e: dst[e]==m} values[e] * x[b, src[e]]
// B=32, N=M=50000, E=1600000.
//
// R6: flat scatter (R1 shape — the only structure that hit high occupancy),
// with two roofline attacks:
//  (a) u64 packed biased-fixed-point atomics: 2 batch lanes per atomic op
//      -> halves the 307 G/s atomic-op cost. bias 2^23/edge, scale 2^19;
//      positive halves => no carry between halves; corrected via per-row
//      degree histogram in the epilogue.
//  (b) xt in bf16 (3.2 MB < 4 MB/XCD L2): gathers become L2-resident 64B
//      lines, removing the ~600 GB/s L3 random-line wall seen in R3-R5.
// Lessons: R1 global f32 atomics write through 4B/op (204.8 MB, 307 G/s);
// R3/R4/R5 looped gather-accum pinned at ~600 GB/s scattered-line service
// regardless of occupancy/MLP — flat beats looped here.

#define BATCH 32

typedef unsigned int       u32;
typedef unsigned long long u64;

#define FSCALE 524288.0f          // 2^19
#define FBIAS  8388608            // 2^23 (per-edge bias, applied in fixed units)
#define INV_FSCALE (1.0f / 524288.0f)

// ---- prep: role A = transpose x (B,N) fp32 -> xtb (N,32) bf16 (as ushort);
//      role B = degree histogram over dst ----
__global__ void k_prep(const float* __restrict__ x, const int* __restrict__ idx,
                       unsigned short* __restrict__ xtb, int* __restrict__ deg,
                       int N, int E, int TB, int HB) {
    if ((int)blockIdx.x < TB) {
        // transpose role: 256 threads, 32x32 tile
        __shared__ float tile[32][33];
        const int n0 = blockIdx.x * 32;
        const int tx = threadIdx.x & 31;
        const int ty = threadIdx.x >> 5;   // 0..7
        #pragma unroll
        for (int k = 0; k < 4; ++k) {
            const int b = ty + 8 * k;
            const int n = n0 + tx;
            tile[tx][b] = (n < N) ? x[(size_t)b * N + n] : 0.0f;
        }
        __syncthreads();
        #pragma unroll
        for (int k = 0; k < 4; ++k) {
            const int r = ty + 8 * k;
            const int n = n0 + r;
            if (n < N) {
                const u32 f = __float_as_uint(tile[r][tx]);
                xtb[(size_t)n * BATCH + tx] = (unsigned short)((f + 0x8000u) >> 16);
            }
        }
    } else {
        // histogram role: grid-stride over edges
        const int bid = (int)blockIdx.x - TB;
        const int stride = HB * (int)blockDim.x;
        for (int e = bid * (int)blockDim.x + (int)threadIdx.x; e < E; e += stride)
            atomicAdd(&deg[idx[E + e]], 1);
    }
}

// ---- scatter: one thread per (edge, batch-pair); u64 fixed-point atomics ----
__global__ void k_scatter(const unsigned short* __restrict__ xtb,
                          const float* __restrict__ values, const int* __restrict__ idx,
                          u64* __restrict__ acc, int E) {
    const int t  = blockIdx.x * blockDim.x + threadIdx.x;
    const int e  = t >> 4;       // edge
    const int b2 = t & 15;       // batch pair (covers b = 2*b2, 2*b2+1)
    if (e < E) {
        const int src = idx[e];
        const int dst = idx[E + e];
        const float v = values[e];
        // two bf16 x-values in one 4B load (coalesced: 16 lanes x 4B = 64B/edge)
        const u32 xp = ((const u32*)xtb)[(size_t)src * 16 + b2];
        const float x0 = __uint_as_float(xp << 16);
        const float x1 = __uint_as_float(xp & 0xFFFF0000u);
        const int f0 = (int)rintf(v * x0 * FSCALE) + FBIAS;
        const int f1 = (int)rintf(v * x1 * FSCALE) + FBIAS;
        const u64 p = (u64)(u32)f0 | ((u64)(u32)f1 << 32);
        atomicAdd(&acc[(size_t)dst * 16 + b2], p);
    }
}

// ---- finish: decode fixed-point, remove bias*deg, add bias, transpose ----
// block = 512 thr: read phase (16 b2 x 32 m), write phase (32 m x 16 b).
__global__ void k_finish(const u64* __restrict__ acc, const int* __restrict__ deg,
                         const float* __restrict__ bias, float* __restrict__ out, int M) {
    __shared__ float tile[32][33];
    const int m0 = blockIdx.x * 32;
    const int t  = threadIdx.x;            // 512
    {
        const int b2 = t & 15;
        const int my = t >> 4;             // 0..31
        const int m  = m0 + my;
        if (m < M) {
            const u64 p  = acc[(size_t)m * 16 + b2];
            const int d  = deg[m];
            const float bi = bias[m];
            const int corr = d * FBIAS;
            const float v0 = (float)((int)(u32)(p & 0xFFFFFFFFu) - corr) * INV_FSCALE + bi;
            const float v1 = (float)((int)(u32)(p >> 32)          - corr) * INV_FSCALE + bi;
            tile[my][2 * b2]     = v0;
            tile[my][2 * b2 + 1] = v1;
        }
    }
    __syncthreads();
    {
        const int mx = t & 31;
        const int by = t >> 5;             // 0..15
        const int m  = m0 + mx;
        if (m < M) {
            out[(size_t)by * M + m]        = tile[mx][by];
            out[(size_t)(by + 16) * M + m] = tile[mx][by + 16];
        }
    }
}

extern "C" void kernel_launch(void* const* d_in, const int* in_sizes, int n_in,
                              void* d_out, int out_size, void* d_ws, size_t ws_size,
                              hipStream_t stream) {
    const float* x      = (const float*)d_in[0];  // (B,N,1) fp32
    const float* values = (const float*)d_in[1];  // (E,)    fp32
    const float* bias   = (const float*)d_in[2];  // (M,1)   fp32
    const int*   idx    = (const int*)d_in[3];    // (2,E)   int32

    const int N = in_sizes[0] / BATCH;   // 50000
    const int E = in_sizes[3] / 2;       // 1600000
    const int M = in_sizes[2];           // 50000

    float* out = (float*)d_out;

    // workspace: acc (M*16 u64, 6.4 MB) | xtb (N*32 bf16, 3.2 MB) | deg (M int)
    char* p = (char*)d_ws;
    u64* acc            = (u64*)p;            p += (size_t)M * 16 * sizeof(u64);
    unsigned short* xtb = (unsigned short*)p; p += (size_t)N * BATCH * sizeof(unsigned short);
    int* deg            = (int*)p;

    hipMemsetAsync(acc, 0, (size_t)M * 16 * sizeof(u64), stream);
    hipMemsetAsync(deg, 0, (size_t)M * sizeof(int), stream);

    const int TB = (N + 31) / 32;        // transpose blocks
    const int HB = 1024;                 // histogram blocks
    k_prep<<<TB + HB, 256, 0, stream>>>(x, idx, xtb, deg, N, E, TB, HB);

    const long long total = (long long)E * 16;
    k_scatter<<<(int)((total + 255) / 256), 256, 0, stream>>>(xtb, values, idx, acc, E);

    k_finish<<<(M + 31) / 32, 512, 0, stream>>>(acc, deg, bias, out, M);
}